// Round 11
// baseline (221.144 us; speedup 1.0000x reference)
//
#include <hip/hip_runtime.h>
#include <hip/hip_bf16.h>
#include <math.h>

// ---------------- constants ----------------
#define NQ    1024
#define CC    128
#define CAM   6
#define RR    4
#define LL    4
#define PP    8
#define HHD   8     // heads
#define HDD   16    // head dim
#define GG    32
#define S_TOT 14960
#define PROPN 28
#define NTAP  27
#define MVAL  (CAM * S_TOT)      // 89760 value rows
#define NVB   ((MVAL + 63) / 64) // 1403 valproj blocks
#define NCVB  (8 * NTAP)         // 216 conv blocks

typedef __attribute__((ext_vector_type(8))) short bf16x8;
typedef __attribute__((ext_vector_type(4))) float f32x4;

__device__ __forceinline__ float gelu_tanh(float x) {
    return 0.5f * x * (1.0f + tanhf(0.7978845608028654f * (x + 0.044715f * x * x * x)));
}

__device__ __forceinline__ unsigned short f2bf(float f) {
    union { float f; unsigned int u; } x; x.f = f;
    unsigned int r = (x.u + 0x7FFFu + ((x.u >> 16) & 1u)) >> 16;
    return (unsigned short)r;
}

__device__ __forceinline__ float bf2f(short s) {
    union { unsigned int u; float f; } x;
    x.u = ((unsigned int)(unsigned short)s) << 16;
    return x.f;
}

// ---------------- D1: all weight transposes + voxel scatter ----------
__global__ void k_wt_scatter(const float* __restrict__ Wsc, unsigned short* __restrict__ WscT,
                             const float* __restrict__ valw, unsigned short* __restrict__ valwT,
                             const float* __restrict__ outw, unsigned short* __restrict__ outwT,
                             const float* __restrict__ p1w, unsigned short* __restrict__ p1wT,
                             const float* __restrict__ f1w, unsigned short* __restrict__ f1wT,
                             const float* __restrict__ f2w, unsigned short* __restrict__ f2wT,
                             const float* __restrict__ offw, unsigned short* __restrict__ offwT,
                             const float* __restrict__ aww, unsigned short* __restrict__ awwT,
                             const float* __restrict__ p2w, unsigned short* __restrict__ p2wT,
                             const float* __restrict__ p2b, float* __restrict__ p2bp,
                             const float* __restrict__ qin, const float* __restrict__ gp,
                             float* __restrict__ grid, float* __restrict__ cnt,
                             int* __restrict__ flatidx) {
    __shared__ float t[64][65];
    __shared__ int sflat[2];
    int z = blockIdx.z;
    int tid = threadIdx.x;

    if (z >= 63) {   // -------- scatter-add into voxel grid (2 queries per block) --------
        int half = tid >> 7, c = tid & 127;
        int n = ((z - 63) * 4 + (blockIdx.x * 2 + blockIdx.y)) * 2 + half;
        if (c == 0) {
            float mx = gp[n * PROPN + 0], my = gp[n * PROPN + 1], mz = gp[n * PROPN + 2];
            int vx = (int)floorf((mx + 4.0f) * 4.0f);
            int vy = (int)floorf((my + 4.0f) * 4.0f);
            int vz = (int)floorf((mz + 4.0f) * 4.0f);
            vx = min(max(vx, 0), GG - 1);
            vy = min(max(vy, 0), GG - 1);
            vz = min(max(vz, 0), GG - 1);
            int f = (vx * GG + vy) * GG + vz;
            sflat[half] = f;
            flatidx[n] = f;
            atomicAdd(&cnt[f], 1.0f);
        }
        __syncthreads();
        atomicAdd(&grid[(size_t)sflat[half] * CC + c], qin[(size_t)n * CC + c]);
        return;
    }

    int n0 = blockIdx.x * 64, k0 = blockIdx.y * 64;
    if (z == 62) {
#pragma unroll
        for (int it = 0; it < 16; ++it) {
            int idx = tid + it * 256;
            int r = idx >> 6, c = idx & 63;
            t[r][c] = (n0 + c < PROPN) ? p2w[(size_t)(k0 + r) * PROPN + n0 + c] : 0.f;
        }
        __syncthreads();
#pragma unroll
        for (int it = 0; it < 16; ++it) {
            int idx = tid + it * 256;
            int r = idx >> 6, c = idx & 63;
            p2wT[(size_t)(n0 + r) * 128 + k0 + c] = f2bf(t[c][r]);
        }
        if (blockIdx.x == 0 && blockIdx.y == 0 && tid < 128)
            p2bp[tid] = (tid < PROPN) ? p2b[tid] : 0.f;
        return;
    }
    const float* src; unsigned short* dst; int ss, ds;
    if (z < 27)       { src = Wsc + (size_t)z * 16384; dst = WscT + (size_t)z * 16384; ss = 128; ds = 128; }
    else if (z == 27) { src = valw; dst = valwT; ss = 128; ds = 128; }
    else if (z == 28) { src = outw; dst = outwT; ss = 128; ds = 128; }
    else if (z == 29) { src = p1w;  dst = p1wT;  ss = 128; ds = 128; }
    else if (z < 34)  { int q = z - 30; src = f1w + q * 128; dst = f1wT + (size_t)q * 16384; ss = 512;  ds = 128; }
    else if (z < 38)  { int q = z - 34; src = f2w + (size_t)q * 16384; dst = f2wT + q * 128; ss = 128;  ds = 512; }
    else if (z < 54)  { int q = z - 38; src = offw + q * 128; dst = offwT + (size_t)q * 16384; ss = 2048; ds = 128; }
    else              { int q = z - 54; src = aww + q * 128;  dst = awwT + (size_t)q * 16384; ss = 1024; ds = 128; }
#pragma unroll
    for (int it = 0; it < 16; ++it) {
        int idx = tid + it * 256;
        int r = idx >> 6, c = idx & 63;
        t[r][c] = src[(size_t)(k0 + r) * ss + n0 + c];
    }
    __syncthreads();
#pragma unroll
    for (int it = 0; it < 16; ++it) {
        int idx = tid + it * 256;
        int r = idx >> 6, c = idx & 63;
        dst[(size_t)(n0 + r) * ds + k0 + c] = f2bf(t[c][r]);
    }
}

// ---------------- D2: conv per-tap (bx<216) || valproj (bx>=216), 33 KB LDS --------------
__global__ __launch_bounds__(256) void k_conv_val(
    const float* __restrict__ grid, const float* __restrict__ cnt,
    const int* __restrict__ flatidx, const unsigned short* __restrict__ WT,
    float* __restrict__ convacc27,
    const float* __restrict__ ms, const unsigned short* __restrict__ valwT,
    const float* __restrict__ valb, unsigned short* __restrict__ value)
{
    __shared__ bf16x8 Bs[128 * 16];   // 32 KB
    __shared__ int   nbase[128];
    __shared__ float nscale[128];
    int bx = blockIdx.x, tid = threadIdx.x;
    int lane = tid & 63, wv = tid >> 6;
    int r = lane & 15, q = lane >> 4;

    if (bx >= NCVB) {   // ---------------- value projection role ----------------
        int vb = bx - NCVB;
        int m0 = vb * 64;
#pragma unroll
        for (int it = 0; it < 8; ++it) {
            int idx = tid + it * 256;
            int n = idx >> 4, c = idx & 15;
            Bs[n * 16 + (c ^ (n & 15))] = *(const bf16x8*)(valwT + (size_t)n * 128 + c * 8);
        }
        __syncthreads();

        int row = m0 + wv * 16 + r;
        int mg = min(row, MVAL - 1);
        const float* pA = ms + (size_t)mg * 128;
        float bia[8];
#pragma unroll
        for (int j = 0; j < 8; ++j) bia[j] = valb[j * 16 + r];

        f32x4 acc[8];
#pragma unroll
        for (int j = 0; j < 8; ++j)
#pragma unroll
            for (int e = 0; e < 4; ++e) acc[j][e] = 0.f;

#pragma unroll
        for (int ks = 0; ks < 4; ++ks) {
            const float* p = pA + ks * 32 + q * 8;
            float4 aa = *(const float4*)p;
            float4 bb = *(const float4*)(p + 4);
            bf16x8 af;
            af[0] = (short)f2bf(aa.x); af[1] = (short)f2bf(aa.y);
            af[2] = (short)f2bf(aa.z); af[3] = (short)f2bf(aa.w);
            af[4] = (short)f2bf(bb.x); af[5] = (short)f2bf(bb.y);
            af[6] = (short)f2bf(bb.z); af[7] = (short)f2bf(bb.w);
            bf16x8 bfr[8];
#pragma unroll
            for (int j = 0; j < 8; ++j)
                bfr[j] = Bs[(j * 16 + r) * 16 + ((ks * 4 + q) ^ r)];
#pragma unroll
            for (int j = 0; j < 8; ++j)
                acc[j] = __builtin_amdgcn_mfma_f32_16x16x32_bf16(af, bfr[j], acc[j], 0, 0, 0);
        }

        // direct head-major store: out row m = m0 + wv*16 + q*4 + e, col = j*16 + r (h=j)
#pragma unroll
        for (int e = 0; e < 4; ++e) {
            int m = m0 + wv * 16 + q * 4 + e;
            if (m < MVAL) {
                int cam = m / S_TOT;
                int s = m - cam * S_TOT;
                int pos, HW, sb;
                if (s < 11264)      { pos = s;          HW = 11264; sb = 0; }
                else if (s < 14080) { pos = s - 11264;  HW = 2816;  sb = 11264; }
                else if (s < 14784) { pos = s - 14080;  HW = 704;   sb = 14080; }
                else                { pos = s - 14784;  HW = 176;   sb = 14784; }
                size_t base = ((size_t)cam * S_TOT + sb) * CC + (size_t)pos * HDD + r;
#pragma unroll
                for (int j = 0; j < 8; ++j)
                    value[base + (size_t)j * (HW * HDD)] = f2bf(acc[j][e] + bia[j]);
            }
        }
        return;
    }

    // ---------------- conv role: one tap per block, A direct from global ----------------
    int tap = bx >> 3;          // 0..26
    int q0 = (bx & 7) * 128;    // query block
    int dz = tap / 9 - 1, dy = (tap / 3) % 3 - 1, dx = tap % 3 - 1;

    if (tid < 128) {
        int f = flatidx[q0 + tid];
        int nx = (f >> 10) + dz, ny = ((f >> 5) & 31) + dy, nz = (f & 31) + dx;
        bool ok = (nx >= 0 && nx < GG && ny >= 0 && ny < GG && nz >= 0 && nz < GG);
        int nf = ok ? (nx * GG + ny) * GG + nz : 0;
        nbase[tid] = nf;
        nscale[tid] = ok ? 1.0f / fmaxf(cnt[nf], 1.0f) : 0.f;
    }
    const unsigned short* Wt = WT + (size_t)tap * CC * CC;
#pragma unroll
    for (int it = 0; it < 8; ++it) {
        int idx = tid + it * 256;
        int n = idx >> 4, c = idx & 15;
        Bs[n * 16 + (c ^ (n & 15))] = *(const bf16x8*)(Wt + (size_t)n * CC + c * 8);
    }
    __syncthreads();

    int wr = (wv >> 1) * 64, wc = (wv & 1) * 64;
    f32x4 acc[4][4];
#pragma unroll
    for (int i = 0; i < 4; ++i)
#pragma unroll
        for (int j = 0; j < 4; ++j)
#pragma unroll
            for (int e = 0; e < 4; ++e) acc[i][j][e] = 0.f;
#pragma unroll
    for (int ks = 0; ks < 4; ++ks) {
        bf16x8 bfr[4];
#pragma unroll
        for (int j = 0; j < 4; ++j)
            bfr[j] = Bs[(wc + j * 16 + r) * 16 + ((ks * 4 + q) ^ r)];
#pragma unroll
        for (int i = 0; i < 4; ++i) {
            int row = wr + i * 16 + r;
            const float* p = grid + (size_t)nbase[row] * CC + (ks * 4 + q) * 8;
            float s = nscale[row];
            float4 aa = *(const float4*)p;
            float4 bb = *(const float4*)(p + 4);
            bf16x8 af;
            af[0] = (short)f2bf(aa.x * s); af[1] = (short)f2bf(aa.y * s);
            af[2] = (short)f2bf(aa.z * s); af[3] = (short)f2bf(aa.w * s);
            af[4] = (short)f2bf(bb.x * s); af[5] = (short)f2bf(bb.y * s);
            af[6] = (short)f2bf(bb.z * s); af[7] = (short)f2bf(bb.w * s);
#pragma unroll
            for (int j = 0; j < 4; ++j)
                acc[i][j] = __builtin_amdgcn_mfma_f32_16x16x32_bf16(af, bfr[j], acc[i][j], 0, 0, 0);
        }
    }
    float* dst = convacc27 + (size_t)tap * NQ * CC;
#pragma unroll
    for (int i = 0; i < 4; ++i)
#pragma unroll
        for (int e = 0; e < 4; ++e) {
            int m = q0 + wr + i * 16 + q * 4 + e;
#pragma unroll
            for (int j = 0; j < 4; ++j) {
                int col = wc + j * 16 + r;
                dst[(size_t)m * CC + col] = acc[i][j][e];
            }
        }
}

// ---------------- D3: LN(conv) + refoff dots (parallel) + projection ----------------
__global__ void k_ln_conv_proj(const float* __restrict__ a, const float* __restrict__ convacc27,
                               const float* __restrict__ bconv,
                               const float* __restrict__ g, const float* __restrict__ be,
                               float* __restrict__ out, unsigned short* __restrict__ outbf,
                               const float* __restrict__ refw, const float* __restrict__ refb,
                               const float* __restrict__ gp, const float* __restrict__ l2i,
                               const float* __restrict__ depth,
                               const int* __restrict__ ih, const int* __restrict__ iw,
                               float* __restrict__ wm, float* __restrict__ r2u,
                               float* __restrict__ r2v) {
    __shared__ float w4[4];
    __shared__ float qrow[CC];
    __shared__ float ro[12];
    int n = blockIdx.x, c = threadIdx.x;
    float apart = 0.f;
#pragma unroll
    for (int t = 0; t < NTAP; ++t) apart += convacc27[((size_t)t * NQ + n) * CC + c];
    float x = a[n * CC + c] + gelu_tanh(apart + bconv[c]);
    float s = x;
#pragma unroll
    for (int d = 1; d < 64; d <<= 1) s += __shfl_xor(s, d);
    if ((c & 63) == 0) w4[c >> 6] = s;
    __syncthreads();
    float m = (w4[0] + w4[1]) * (1.0f / CC);
    float dd = x - m;
    float v = dd * dd;
#pragma unroll
    for (int d = 1; d < 64; d <<= 1) v += __shfl_xor(v, d);
    if ((c & 63) == 0) w4[2 + (c >> 6)] = v;
    __syncthreads();
    float var = (w4[2] + w4[3]) * (1.0f / CC);
    float qv = dd * rsqrtf(var + 1e-5f) * g[c] + be[c];
    out[n * CC + c] = qv;
    outbf[n * CC + c] = f2bf(qv);
    qrow[c] = qv;
    __syncthreads();
    // refoff dots: 12 dots x 8 threads x 16 elems + shfl reduce (width 8)
    if (c < 96) {
        int dg = c >> 3, ll = c & 7;
        float sacc = 0.f;
#pragma unroll
        for (int k = 0; k < 16; ++k) {
            int kk = ll * 16 + k;
            sacc += qrow[kk] * refw[kk * 12 + dg];
        }
#pragma unroll
        for (int d = 4; d; d >>= 1) sacc += __shfl_xor(sacc, d, 8);
        if (ll == 0) ro[dg] = sacc + refb[dg];
    }
    __syncthreads();
    if (c < 24) {
        int cam = c >> 2, r = c & 3;
        float fH = (float)(*ih), fW = (float)(*iw);
        const float* M = l2i + cam * 16;
        float px = gp[n * PROPN + 0] + ro[r * 3 + 0];
        float py = gp[n * PROPN + 1] + ro[r * 3 + 1];
        float pz = gp[n * PROPN + 2] + ro[r * 3 + 2];
        float p0 = M[0] * px + M[1] * py + M[2]  * pz + M[3];
        float p1 = M[4] * px + M[5] * py + M[6]  * pz + M[7];
        float p2 = M[8] * px + M[9] * py + M[10] * pz + M[11];
        float zc = fmaxf(p2, 1e-5f);
        float u = p0 / zc, vv = p1 / zc;
        bool valid = (p2 > 1e-5f) && (u >= 0.f) && (u < fW) && (vv >= 0.f) && (vv < fH);
        int iu = min(max((int)(u / fW * 176.f), 0), 175);
        int iv = min(max((int)(vv / fH * 64.f), 0), 63);
        float ds = depth[cam * 64 * 176 + iv * 176 + iu];
        int o = cam * (NQ * RR) + n * RR + r;
        wm[o]  = valid ? expf(-fabsf(p2 - ds)) : 0.f;
        r2u[o] = u / fW;
        r2v[o] = vv / fH;
    }
}

// ---------------- D4: off + attn GEMMs, 64-row m-blocks (384 blocks) ----------
__global__ __launch_bounds__(256) void k_qhead(
    const unsigned short* __restrict__ Abf,
    const unsigned short* __restrict__ offwT, const float* __restrict__ offb,
    unsigned short* __restrict__ offsb,
    const unsigned short* __restrict__ awwT, const float* __restrict__ awb,
    unsigned short* __restrict__ attn)
{
    __shared__ bf16x8 Bs[128 * 16];   // 32 KB
    int bx = blockIdx.x, tid = threadIdx.x;
    int lane = tid & 63, wv = tid >> 6;
    int r = lane & 15, q = lane >> 4;
    bool isoff = bx < 16;
    int n0 = (isoff ? bx : (bx - 16)) * 128;
    const unsigned short* WT = isoff ? offwT : awwT;
    int m0 = blockIdx.y * 64;
    int mw = m0 + wv * 16;

#pragma unroll
    for (int it = 0; it < 8; ++it) {
        int idx = tid + it * 256;
        int n = idx >> 4, c = idx & 15;
        Bs[n * 16 + (c ^ (n & 15))] = *(const bf16x8*)(WT + (size_t)(n0 + n) * 128 + c * 8);
    }
    __syncthreads();

    f32x4 acc[8];
#pragma unroll
    for (int j = 0; j < 8; ++j)
#pragma unroll
        for (int e = 0; e < 4; ++e) acc[j][e] = 0.f;

#pragma unroll
    for (int ks = 0; ks < 4; ++ks) {
        bf16x8 af = *(const bf16x8*)(Abf + (size_t)(mw + r) * 128 + (ks * 4 + q) * 8);
#pragma unroll
        for (int j = 0; j < 8; ++j) {
            bf16x8 b = Bs[(j * 16 + r) * 16 + ((ks * 4 + q) ^ r)];
            acc[j] = __builtin_amdgcn_mfma_f32_16x16x32_bf16(af, b, acc[j], 0, 0, 0);
        }
    }

    float bia[8];
    const float* bsrc = isoff ? offb : awb;
#pragma unroll
    for (int j = 0; j < 8; ++j) bia[j] = bsrc[n0 + j * 16 + r];

    if (isoff) {
#pragma unroll
        for (int e = 0; e < 4; ++e) {
            int m = mw + q * 4 + e;
            unsigned short* orow = offsb + (size_t)m * 2048 + n0;
#pragma unroll
            for (int j = 0; j < 8; ++j)
                orow[j * 16 + r] = f2bf(acc[j][e] + bia[j]);
        }
    } else {
#pragma unroll
        for (int e = 0; e < 4; ++e) {
            float mx = -1e30f;
#pragma unroll
            for (int j = 0; j < 8; ++j) mx = fmaxf(mx, acc[j][e] + bia[j]);
#pragma unroll
            for (int d = 1; d < 16; d <<= 1) mx = fmaxf(mx, __shfl_xor(mx, d));
            float ex[8];
            float sum = 0.f;
#pragma unroll
            for (int j = 0; j < 8; ++j) { ex[j] = expf(acc[j][e] + bia[j] - mx); sum += ex[j]; }
#pragma unroll
            for (int d = 1; d < 16; d <<= 1) sum += __shfl_xor(sum, d);
            float inv = 1.0f / sum;
            int m = mw + q * 4 + e;
            unsigned short* orow = attn + (size_t)m * 1024 + n0;
#pragma unroll
            for (int j = 0; j < 8; ++j)
                orow[j * 16 + r] = f2bf(ex[j] * inv);
        }
    }
}

// ---------------- deformable sampling, head-major value, 1024 threads (4-way cr split) ----
__global__ __launch_bounds__(1024) void k_sample(
                         const unsigned short* __restrict__ value,
                         const unsigned short* __restrict__ offsb,
                         const unsigned short* __restrict__ attn,
                         const float* __restrict__ wm,
                         const float* __restrict__ r2u, const float* __restrict__ r2v,
                         float* __restrict__ sampout) {
    const int Wl_[4] = {176, 88, 44, 22};
    const int Hl_[4] = {64, 32, 16, 8};
    const int s0_[4] = {0, 11264, 14080, 14784};
    int n = blockIdx.x, tid = threadIdx.x;
    __shared__ float s_attn[1024];
    __shared__ float s_offs[2048];
    __shared__ float s_wm[24], s_ru[24], s_rv[24];
    __shared__ float part[3][HHD][HDD];

    if (tid < 128) {
        bf16x8 v = *(const bf16x8*)(attn + (size_t)n * 1024 + tid * 8);
#pragma unroll
        for (int d = 0; d < 8; ++d) s_attn[tid * 8 + d] = bf2f(v[d]);
    }
    if (tid >= 128 && tid < 384) {
        int t = tid - 128;
        bf16x8 v = *(const bf16x8*)(offsb + (size_t)n * 2048 + t * 8);
#pragma unroll
        for (int d = 0; d < 8; ++d) s_offs[t * 8 + d] = bf2f(v[d]);
    }
    if (tid >= 384 && tid < 408) {
        int t = tid - 384;
        int cam = t >> 2, r = t & 3;
        int o = cam * (NQ * RR) + n * RR + r;
        s_wm[t] = wm[o]; s_ru[t] = r2u[o]; s_rv[t] = r2v[o];
    }
    __syncthreads();

    int quarter = tid >> 8;       // 0..3: cr range [quarter*6, +6)
    int t8 = tid & 255;
    int h = t8 >> 5, slot = t8 & 31;
    int l = slot >> 3, p = slot & 7;
    int Wl = Wl_[l], Hl = Hl_[l];
    float fWl = (float)Wl, fHl = (float)Hl;
    size_t planeC = (size_t)s0_[l] * CC + (size_t)h * (Hl * Wl * HDD);
    float acc[16];
#pragma unroll
    for (int d = 0; d < 16; ++d) acc[d] = 0.f;

    for (int cr = quarter * 6; cr < quarter * 6 + 6; ++cr) {
        int cam = cr >> 2, r = cr & 3;
        float ws = s_attn[h * 128 + r * 32 + l * 8 + p] * s_wm[cr];
        if (ws == 0.f) continue;
        float ox = s_offs[h * 256 + r * 64 + l * 16 + p * 2 + 0];
        float oy = s_offs[h * 256 + r * 64 + l * 16 + p * 2 + 1];
        float x = s_ru[cr] * fWl + ox - 0.5f;
        float y = s_rv[cr] * fHl + oy - 0.5f;
        float xf = floorf(x), yf = floorf(y);
        float wx = x - xf, wy = y - yf;
        int x0 = min(max((int)xf, 0), Wl - 1);
        int x1 = min(max((int)xf + 1, 0), Wl - 1);
        int y0 = min(max((int)yf, 0), Hl - 1);
        int y1 = min(max((int)yf + 1, 0), Hl - 1);
        const unsigned short* base = value + (size_t)cam * S_TOT * CC + planeC;
        const unsigned short* p00 = base + (size_t)(y0 * Wl + x0) * HDD;
        const unsigned short* p01 = base + (size_t)(y0 * Wl + x1) * HDD;
        const unsigned short* p10 = base + (size_t)(y1 * Wl + x0) * HDD;
        const unsigned short* p11 = base + (size_t)(y1 * Wl + x1) * HDD;
        float w00 = ws * (1.f - wx) * (1.f - wy);
        float w01 = ws * wx * (1.f - wy);
        float w10 = ws * (1.f - wx) * wy;
        float w11 = ws * wx * wy;
        bf16x8 va0 = *(const bf16x8*)p00, va1 = *(const bf16x8*)(p00 + 8);
        bf16x8 vb0 = *(const bf16x8*)p01, vb1 = *(const bf16x8*)(p01 + 8);
        bf16x8 vc0 = *(const bf16x8*)p10, vc1 = *(const bf16x8*)(p10 + 8);
        bf16x8 vd0 = *(const bf16x8*)p11, vd1 = *(const bf16x8*)(p11 + 8);
#pragma unroll
        for (int d = 0; d < 8; ++d)
            acc[d] += w00 * bf2f(va0[d]) + w01 * bf2f(vb0[d]) + w10 * bf2f(vc0[d]) + w11 * bf2f(vd0[d]);
#pragma unroll
        for (int d = 0; d < 8; ++d)
            acc[8 + d] += w00 * bf2f(va1[d]) + w01 * bf2f(vb1[d]) + w10 * bf2f(vc1[d]) + w11 * bf2f(vd1[d]);
    }

#pragma unroll
    for (int d = 0; d < 16; ++d) {
        float a = acc[d];
#pragma unroll
        for (int s = 16; s >= 1; s >>= 1) a += __shfl_xor(a, s, 32);
        acc[d] = a;
    }
    if (quarter > 0 && slot == 0) {
#pragma unroll
        for (int d = 0; d < 16; ++d) part[quarter - 1][h][d] = acc[d];
    }
    __syncthreads();
    if (quarter == 0 && slot == 0) {
#pragma unroll
        for (int d = 0; d < 16; ++d)
            sampout[(size_t)n * CC + h * HDD + d] =
                acc[d] + part[0][h][d] + part[1][h][d] + part[2][h][d];
    }
}

// ---------------- fused tail: M=16/block, 64 blocks x 512 threads (8 waves, 16 cols/wave) --
__global__ __launch_bounds__(512) void k_tail(
    const float* __restrict__ sampout,
    const unsigned short* __restrict__ outwT, const float* __restrict__ outb,
    const float* __restrict__ q1, const float* __restrict__ ang, const float* __restrict__ anb,
    const unsigned short* __restrict__ f1wT, const float* __restrict__ f1b,
    const unsigned short* __restrict__ f2wT, const float* __restrict__ f2b,
    const float* __restrict__ fng, const float* __restrict__ fnb,
    const unsigned short* __restrict__ p1wT, const float* __restrict__ p1b,
    const unsigned short* __restrict__ p2wT, const float* __restrict__ p2bp,
    const float* __restrict__ gp, float* __restrict__ outq, float* __restrict__ outp)
{
    __shared__ bf16x8 As[16 * 16];       // 4 KB
    __shared__ bf16x8 Aff[16 * 64];      // 16 KB  (FFN1 out 16x512; aliased as As2 16x128)
    __shared__ float xrow[16 * 128];     // 8 KB
    __shared__ float q2s[16 * 128];      // 8 KB   -> total 36 KB
    unsigned short* Affu = (unsigned short*)Aff;
    unsigned short* As2u = (unsigned short*)Aff;
    int tid = threadIdx.x, m0 = blockIdx.x * 16;
    int lane = tid & 63, wv = tid >> 6;  // 8 waves
    int wc = wv * 16;                    // each wave owns 16 output cols
    int r = lane & 15, q = lane >> 4;
    int lrow = tid >> 5, ls = tid & 31;  // LN: 32 threads per row

    // pre-issue GEMM1 B (out-proj) into registers before any barrier
    bf16x8 b1[4];
#pragma unroll
    for (int ks = 0; ks < 4; ++ks)
        b1[ks] = *(const bf16x8*)(outwT + (size_t)(wc + r) * 128 + (ks * 4 + q) * 8);

    // stage A (sampout rows m0..m0+15), 256 threads = 16 rows x 16 chunks
    if (tid < 256) {
        int m = tid >> 4, c = tid & 15;
        const float* p = sampout + (size_t)(m0 + m) * 128 + c * 8;
        float4 a = *(const float4*)p;
        float4 b = *(const float4*)(p + 4);
        bf16x8 u;
        u[0] = (short)f2bf(a.x); u[1] = (short)f2bf(a.y);
        u[2] = (short)f2bf(a.z); u[3] = (short)f2bf(a.w);
        u[4] = (short)f2bf(b.x); u[5] = (short)f2bf(b.y);
        u[6] = (short)f2bf(b.z); u[7] = (short)f2bf(b.w);
        As[m * 16 + (c ^ m)] = u;
    }
    __syncthreads();

    f32x4 acc;
    bf16x8 a4[4];
    // ---- GEMM1: out-proj ----
#pragma unroll
    for (int ks = 0; ks < 4; ++ks) a4[ks] = As[r * 16 + ((ks * 4 + q) ^ r)];
#pragma unroll
    for (int e = 0; e < 4; ++e) acc[e] = 0.f;
#pragma unroll
    for (int ks = 0; ks < 4; ++ks)
        acc = __builtin_amdgcn_mfma_f32_16x16x32_bf16(a4[ks], b1[ks], acc, 0, 0, 0);
#pragma unroll
    for (int e = 0; e < 4; ++e) {
        int ml = q * 4 + e;
        int cl = wc + r;
        xrow[ml * 128 + cl] = acc[e] + outb[cl] + q1[(size_t)(m0 + ml) * 128 + cl];
    }
    __syncthreads();

    // ---- LN1 -> q2s ----
    {
        float* xr = xrow + lrow * 128;
        float sum = 0.f;
#pragma unroll
        for (int e = ls; e < 128; e += 32) sum += xr[e];
#pragma unroll
        for (int d = 16; d; d >>= 1) sum += __shfl_xor(sum, d, 32);
        float mean = sum * (1.0f / 128.0f);
        float var = 0.f;
#pragma unroll
        for (int e = ls; e < 128; e += 32) { float dd = xr[e] - mean; var += dd * dd; }
#pragma unroll
        for (int d = 16; d; d >>= 1) var += __shfl_xor(var, d, 32);
        float rstd = rsqrtf(var * (1.0f / 128.0f) + 1e-5f);
#pragma unroll
        for (int e = ls; e < 128; e += 32)
            q2s[lrow * 128 + e] = (xr[e] - mean) * rstd * ang[e] + anb[e];
    }
    __syncthreads();
    if (tid < 256) {   // pack q2 -> As
        int m = tid >> 4, c = tid & 15;
        const float* p = q2s + m * 128 + c * 8;
        bf16x8 u;
#pragma unroll
        for (int d = 0; d < 8; ++d) u[d] = (short)f2bf(p[d]);
        As[m * 16 + (c ^ m)] = u;
    }
    __syncthreads();

    // ---- GEMM2: FFN1 over 4 col-chunks, reg-double-buffered B, no barriers ----
#pragma unroll
    for (int ks = 0; ks < 4; ++ks) a4[ks] = As[r * 16 + ((ks * 4 + q) ^ r)];
    bf16x8 bcur[4];
#pragma unroll
    for (int ks = 0; ks < 4; ++ks)
        bcur[ks] = *(const bf16x8*)(f1wT + (size_t)(wc + r) * 128 + (ks * 4 + q) * 8);
#pragma unroll
    for (int nt = 0; nt < 4; ++nt) {
        bf16x8 bnx[4];
        if (nt < 3) {
#pragma unroll
            for (int ks = 0; ks < 4; ++ks)
                bnx[ks] = *(const bf16x8*)(f1wT + (size_t)(nt + 1) * 16384
                                            + (size_t)(wc + r) * 128 + (ks * 4 + q) * 8);
        }
#pragma unroll
        for (int e = 0; e < 4; ++e) acc[e] = 0.f;
#pragma unroll
        for (int ks = 0; ks < 4; ++ks)
            acc = __builtin_amdgcn_mfma_f32_16x16x32_bf16(a4[ks], bcur[ks], acc, 0, 0, 0);
#pragma unroll
        for (int e = 0; e < 4; ++e) {
            int ml = q * 4 + e;
            int col = nt * 128 + wc + r;
            float v = gelu_tanh(acc[e] + f1b[col]);
            Affu[(ml * 64 + ((col >> 3) ^ ml)) * 8 + (col & 7)] = f2bf(v);
        }
        if (nt < 3) {
#pragma unroll
            for (int ks = 0; ks < 4; ++ks) bcur[ks] = bnx[ks];
        }
    }
    __syncthreads();

    // ---- GEMM3: FFN2 (K=512) accumulate over 4 k-chunks, reg-double-buffered B ----
#pragma unroll
    for (int e = 0; e < 4; ++e) acc[e] = 0.f;
#pragma unroll
    for (int ks = 0; ks < 4; ++ks)
        bcur[ks] = *(const bf16x8*)(f2wT + (size_t)(wc + r) * 512 + (ks * 4 + q) * 8);
#pragma unroll
    for (int kc = 0; kc < 4; ++kc) {
        bf16x8 bnx[4];
        if (kc < 3) {
#pragma unroll
            for (int ks = 0; ks < 4; ++ks)
                bnx[ks] = *(const bf16x8*)(f2wT + (size_t)(wc + r) * 512
                                            + ((kc + 1) * 16 + ks * 4 + q) * 8);
        }
#pragma unroll
        for (int ks = 0; ks < 4; ++ks) {
            bf16x8 af = Aff[r * 64 + ((kc * 16 + ks * 4 + q) ^ r)];
            acc = __builtin_amdgcn_mfma_f32_16x16x32_bf16(af, bcur[ks], acc, 0, 0, 0);
        }
        if (kc < 3) {
#pragma unroll
            for (int ks = 0; ks < 4; ++ks) bcur[ks] = bnx[ks];
        }
    }
#pragma unroll
    for (int e = 0; e < 4; ++e) {
        int ml = q * 4 + e;
        int cl = wc + r;
        xrow[ml * 128 + cl] = acc[e] + f2b[cl] + q2s[ml * 128 + cl];
    }
    __syncthreads();

    // ---- LN2 -> outq + q2s ----
    {
        float* xr = xrow + lrow * 128;
        float sum = 0.f;
#pragma unroll
        for (int e = ls; e < 128; e += 32) sum += xr[e];
#pragma unroll
        for (int d = 16; d; d >>= 1) sum += __shfl_xor(sum, d, 32);
        float mean = sum * (1.0f / 128.0f);
        float var = 0.f;
#pragma unroll
        for (int e = ls; e < 128; e += 32) { float dd = xr[e] - mean; var += dd * dd; }
#pragma unroll
        for (int d = 16; d; d >>= 1) var += __shfl_xor(var, d, 32);
        float rstd = rsqrtf(var * (1.0f / 128.0f) + 1e-5f);
        float* oq = outq + (size_t)(m0 + lrow) * 128;
#pragma unroll
        for (int e = ls; e < 128; e += 32) {
            float v = (xr[e] - mean) * rstd * fng[e] + fnb[e];
            oq[e] = v;
            q2s[lrow * 128 + e] = v;
        }
    }
    __syncthreads();
    if (tid < 256) {   // pack LN2 -> As
        int m = tid >> 4, c = tid & 15;
        const float* p = q2s + m * 128 + c * 8;
        bf16x8 u;
#pragma unroll
        for (int d = 0; d < 8; ++d) u[d] = (short)f2bf(p[d]);
        As[m * 16 + (c ^ m)] = u;
    }
    __syncthreads();

    // ---- GEMM4: p1 -> gelu -> As2 (aliases Aff) ----
#pragma unroll
    for (int ks = 0; ks < 4; ++ks) a4[ks] = As[r * 16 + ((ks * 4 + q) ^ r)];
    bf16x8 bcur2[4];
#pragma unroll
    for (int ks = 0; ks < 4; ++ks)
        bcur2[ks] = *(const bf16x8*)(p1wT + (size_t)(wc + r) * 128 + (ks * 4 + q) * 8);
    // pre-issue p2 B loads (held in b1) to hide latency under GEMM4
#pragma unroll
    for (int ks = 0; ks < 4; ++ks)
        b1[ks] = *(const bf16x8*)(p2wT + (size_t)(wc + r) * 128 + (ks * 4 + q) * 8);
#pragma unroll
    for (int e = 0; e < 4; ++e) acc[e] = 0.f;
#pragma unroll
    for (int ks = 0; ks < 4; ++ks)
        acc = __builtin_amdgcn_mfma_f32_16x16x32_bf16(a4[ks], bcur2[ks], acc, 0, 0, 0);
#pragma unroll
    for (int e = 0; e < 4; ++e) {
        int ml = q * 4 + e;
        int cl = wc + r;
        float v = gelu_tanh(acc[e] + p1b[cl]);
        As2u[(ml * 16 + ((cl >> 3) ^ ml)) * 8 + (cl & 7)] = f2bf(v);
    }
    __syncthreads();

    // ---- GEMM5: p2 + gp resid -> outp ----
#pragma unroll
    for (int e = 0; e < 4; ++e) acc[e] = 0.f;
#pragma unroll
    for (int ks = 0; ks < 4; ++ks) {
        bf16x8 af = Aff[r * 16 + ((ks * 4 + q) ^ r)];   // As2 view
        acc = __builtin_amdgcn_mfma_f32_16x16x32_bf16(af, b1[ks], acc, 0, 0, 0);
    }
#pragma unroll
    for (int e = 0; e < 4; ++e) {
        int m = m0 + q * 4 + e;
        int cl = wc + r;
        if (cl < PROPN)
            outp[(size_t)m * PROPN + cl] = acc[e] + p2bp[cl] + gp[(size_t)m * PROPN + cl];
    }
}

// ---------------- launch ----------------
extern "C" void kernel_launch(void* const* d_in, const int* in_sizes, int n_in,
                              void* d_out, int out_size, void* d_ws, size_t ws_size,
                              hipStream_t stream) {
    const float* query = (const float*)d_in[0];
    const float* gp    = (const float*)d_in[1];
    const float* ms    = (const float*)d_in[2];
    const float* depth = (const float*)d_in[3];
    const float* l2i   = (const float*)d_in[4];
    const int*   ih    = (const int*)d_in[5];
    const int*   iw    = (const int*)d_in[6];
    const float* Wsc   = (const float*)d_in[7];
    const float* bsc   = (const float*)d_in[8];
    const float* scg   = (const float*)d_in[9];
    const float* scb   = (const float*)d_in[10];
    const float* refw  = (const float*)d_in[11];
    const float* refb  = (const float*)d_in[12];
    const float* offw  = (const float*)d_in[13];
    const float* offbi = (const float*)d_in[14];
    const float* aww   = (const float*)d_in[15];
    const float* awb   = (const float*)d_in[16];
    const float* valw  = (const float*)d_in[17];
    const float* valb  = (const float*)d_in[18];
    const float* outw  = (const float*)d_in[19];
    const float* outb  = (const float*)d_in[20];
    const float* ang   = (const float*)d_in[21];
    const float* anb   = (const float*)d_in[22];
    const float* f1w   = (const float*)d_in[23];
    const float* f1b   = (const float*)d_in[24];
    const float* f2w   = (const float*)d_in[25];
    const float* f2b   = (const float*)d_in[26];
    const float* fng   = (const float*)d_in[27];
    const float* fnb   = (const float*)d_in[28];
    const float* p1w   = (const float*)d_in[29];
    const float* p1b   = (const float*)d_in[30];
    const float* p2w   = (const float*)d_in[31];
    const float* p2b   = (const float*)d_in[32];

    float* outq = (float*)d_out;            // 1024*128
    float* outp = outq + NQ * CC;           // 1024*28

    float* ws = (float*)d_ws;
    size_t o = 0;
    float* grid    = ws + o; o += (size_t)GG * GG * GG * CC;
    float* cnt     = ws + o; o += GG * GG * GG;
    size_t zero_floats = o;                 // zero grid+cnt only
    int*   flatidx = (int*)(ws + o); o += NQ;
    float* convacc27 = ws + o; o += (size_t)NTAP * NQ * CC;
    float* q1      = ws + o; o += NQ * CC;
    float* wm      = ws + o; o += CAM * NQ * RR;
    float* r2u     = ws + o; o += CAM * NQ * RR;
    float* r2v     = ws + o; o += CAM * NQ * RR;
    float* sampout = ws + o; o += NQ * CC;
    float* p2bp    = ws + o; o += 128;
    unsigned short* u16base = (unsigned short*)(ws + o);
    size_t uo = 0;
    unsigned short* value = u16base + uo; uo += (size_t)CAM * S_TOT * CC;
    unsigned short* offsb = u16base + uo; uo += (size_t)NQ * 2048;
    unsigned short* attn  = u16base + uo; uo += (size_t)NQ * 1024;
    unsigned short* q1bf  = u16base + uo; uo += (size_t)NQ * CC;
    unsigned short* offwT = u16base + uo; uo += (size_t)2048 * 128;
    unsigned short* awwT  = u16base + uo; uo += (size_t)1024 * 128;
    unsigned short* valwT = u16base + uo; uo += 128 * 128;
    unsigned short* outwT = u16base + uo; uo += 128 * 128;
    unsigned short* f1wT  = u16base + uo; uo += 512 * 128;
    unsigned short* f2wT  = u16base + uo; uo += 128 * 512;
    unsigned short* p1wT  = u16base + uo; uo += 128 * 128;
    unsigned short* p2wT  = u16base + uo; uo += 128 * 128;
    unsigned short* WscT  = u16base + uo; uo += (size_t)27 * 128 * 128;
    (void)ws_size; (void)in_sizes; (void)n_in; (void)out_size;

    hipMemsetAsync(ws, 0, zero_floats * sizeof(float), stream);

    // D1: z<63 all weight transposes; z in [63,191): voxel scatter (2 queries/block)
    k_wt_scatter<<<dim3(2, 2, 63 + 128), 256, 0, stream>>>(
        Wsc, WscT, valw, valwT, outw, outwT, p1w, p1wT, f1w, f1wT, f2w, f2wT,
        offw, offwT, aww, awwT, p2w, p2wT, p2b, p2bp,
        query, gp, grid, cnt, flatidx);

    // D2: bx<216 conv per-tap (A direct); bx>=216 valproj (33 KB LDS)
    k_conv_val<<<dim3(NCVB + NVB), 256, 0, stream>>>(
        grid, cnt, flatidx, WscT, convacc27,
        ms, valwT, valb, value);

    // D3: LN + refoff + projection
    k_ln_conv_proj<<<NQ, CC, 0, stream>>>(
        query, convacc27, bsc, scg, scb, q1, q1bf,
        refw, refb, gp, l2i, depth, ih, iw, wm, r2u, r2v);

    // D4: off/attn GEMMs, 64-row m-blocks
    k_qhead<<<dim3(24, 16), 256, 0, stream>>>(q1bf, offwT, offbi, offsb, awwT, awb, attn);

    k_sample<<<NQ, 1024, 0, stream>>>(value, offsb, attn, wm, r2u, r2v, sampout);

    k_tail<<<64, 512, 0, stream>>>(sampout, outwT, outb, q1, ang, anb,
                                   f1wT, f1b, f2wT, f2b, fng, fnb,
                                   p1wT, p1b, p2wT, p2bp, gp, outq, outp);
}

// Round 12
// 213.760 us; speedup vs baseline: 1.0345x; 1.0345x over previous
//
#include <hip/hip_runtime.h>
#include <hip/hip_bf16.h>
#include <math.h>

// ---------------- constants ----------------
#define NQ    1024
#define CC    128
#define CAM   6
#define RR    4
#define LL    4
#define PP    8
#define HHD   8     // heads
#define HDD   16    // head dim
#define GG    32
#define S_TOT 14960
#define PROPN 28
#define NTAP  27
#define MVAL  (CAM * S_TOT)      // 89760 value rows
#define NVB   ((MVAL + 63) / 64) // 1403 valproj blocks
#define NCVB  (8 * NTAP)         // 216 conv blocks

typedef __attribute__((ext_vector_type(8))) short bf16x8;
typedef __attribute__((ext_vector_type(4))) float f32x4;

__device__ __forceinline__ float gelu_tanh(float x) {
    return 0.5f * x * (1.0f + tanhf(0.7978845608028654f * (x + 0.044715f * x * x * x)));
}

__device__ __forceinline__ unsigned short f2bf(float f) {
    union { float f; unsigned int u; } x; x.f = f;
    unsigned int r = (x.u + 0x7FFFu + ((x.u >> 16) & 1u)) >> 16;
    return (unsigned short)r;
}

__device__ __forceinline__ float bf2f(short s) {
    union { unsigned int u; float f; } x;
    x.u = ((unsigned int)(unsigned short)s) << 16;
    return x.f;
}

// ---------------- D1: all weight transposes + voxel scatter ----------
__global__ void k_wt_scatter(const float* __restrict__ Wsc, unsigned short* __restrict__ WscT,
                             const float* __restrict__ valw, unsigned short* __restrict__ valwT,
                             const float* __restrict__ outw, unsigned short* __restrict__ outwT,
                             const float* __restrict__ p1w, unsigned short* __restrict__ p1wT,
                             const float* __restrict__ f1w, unsigned short* __restrict__ f1wT,
                             const float* __restrict__ f2w, unsigned short* __restrict__ f2wT,
                             const float* __restrict__ offw, unsigned short* __restrict__ offwT,
                             const float* __restrict__ aww, unsigned short* __restrict__ awwT,
                             const float* __restrict__ p2w, unsigned short* __restrict__ p2wT,
                             const float* __restrict__ p2b, float* __restrict__ p2bp,
                             const float* __restrict__ qin, const float* __restrict__ gp,
                             float* __restrict__ grid, float* __restrict__ cnt,
                             int* __restrict__ flatidx) {
    __shared__ float t[64][65];
    __shared__ int sflat[2];
    int z = blockIdx.z;
    int tid = threadIdx.x;

    if (z >= 63) {   // -------- scatter-add into voxel grid (2 queries per block) --------
        int half = tid >> 7, c = tid & 127;
        int n = ((z - 63) * 4 + (blockIdx.x * 2 + blockIdx.y)) * 2 + half;
        if (c == 0) {
            float mx = gp[n * PROPN + 0], my = gp[n * PROPN + 1], mz = gp[n * PROPN + 2];
            int vx = (int)floorf((mx + 4.0f) * 4.0f);
            int vy = (int)floorf((my + 4.0f) * 4.0f);
            int vz = (int)floorf((mz + 4.0f) * 4.0f);
            vx = min(max(vx, 0), GG - 1);
            vy = min(max(vy, 0), GG - 1);
            vz = min(max(vz, 0), GG - 1);
            int f = (vx * GG + vy) * GG + vz;
            sflat[half] = f;
            flatidx[n] = f;
            atomicAdd(&cnt[f], 1.0f);
        }
        __syncthreads();
        atomicAdd(&grid[(size_t)sflat[half] * CC + c], qin[(size_t)n * CC + c]);
        return;
    }

    int n0 = blockIdx.x * 64, k0 = blockIdx.y * 64;
    if (z == 62) {
#pragma unroll
        for (int it = 0; it < 16; ++it) {
            int idx = tid + it * 256;
            int r = idx >> 6, c = idx & 63;
            t[r][c] = (n0 + c < PROPN) ? p2w[(size_t)(k0 + r) * PROPN + n0 + c] : 0.f;
        }
        __syncthreads();
#pragma unroll
        for (int it = 0; it < 16; ++it) {
            int idx = tid + it * 256;
            int r = idx >> 6, c = idx & 63;
            p2wT[(size_t)(n0 + r) * 128 + k0 + c] = f2bf(t[c][r]);
        }
        if (blockIdx.x == 0 && blockIdx.y == 0 && tid < 128)
            p2bp[tid] = (tid < PROPN) ? p2b[tid] : 0.f;
        return;
    }
    const float* src; unsigned short* dst; int ss, ds;
    if (z < 27)       { src = Wsc + (size_t)z * 16384; dst = WscT + (size_t)z * 16384; ss = 128; ds = 128; }
    else if (z == 27) { src = valw; dst = valwT; ss = 128; ds = 128; }
    else if (z == 28) { src = outw; dst = outwT; ss = 128; ds = 128; }
    else if (z == 29) { src = p1w;  dst = p1wT;  ss = 128; ds = 128; }
    else if (z < 34)  { int q = z - 30; src = f1w + q * 128; dst = f1wT + (size_t)q * 16384; ss = 512;  ds = 128; }
    else if (z < 38)  { int q = z - 34; src = f2w + (size_t)q * 16384; dst = f2wT + q * 128; ss = 128;  ds = 512; }
    else if (z < 54)  { int q = z - 38; src = offw + q * 128; dst = offwT + (size_t)q * 16384; ss = 2048; ds = 128; }
    else              { int q = z - 54; src = aww + q * 128;  dst = awwT + (size_t)q * 16384; ss = 1024; ds = 128; }
#pragma unroll
    for (int it = 0; it < 16; ++it) {
        int idx = tid + it * 256;
        int r = idx >> 6, c = idx & 63;
        t[r][c] = src[(size_t)(k0 + r) * ss + n0 + c];
    }
    __syncthreads();
#pragma unroll
    for (int it = 0; it < 16; ++it) {
        int idx = tid + it * 256;
        int r = idx >> 6, c = idx & 63;
        dst[(size_t)(n0 + r) * ds + k0 + c] = f2bf(t[c][r]);
    }
}

// ---------------- D2: conv per-tap (bx<216) || valproj (bx>=216), 33 KB LDS --------------
__global__ __launch_bounds__(256) void k_conv_val(
    const float* __restrict__ grid, const float* __restrict__ cnt,
    const int* __restrict__ flatidx, const unsigned short* __restrict__ WT,
    float* __restrict__ convacc27,
    const float* __restrict__ ms, const unsigned short* __restrict__ valwT,
    const float* __restrict__ valb, unsigned short* __restrict__ value)
{
    __shared__ bf16x8 Bs[128 * 16];   // 32 KB
    __shared__ int   nbase[128];
    __shared__ float nscale[128];
    int bx = blockIdx.x, tid = threadIdx.x;
    int lane = tid & 63, wv = tid >> 6;
    int r = lane & 15, q = lane >> 4;

    if (bx >= NCVB) {   // ---------------- value projection role ----------------
        int vb = bx - NCVB;
        int m0 = vb * 64;
#pragma unroll
        for (int it = 0; it < 8; ++it) {
            int idx = tid + it * 256;
            int n = idx >> 4, c = idx & 15;
            Bs[n * 16 + (c ^ (n & 15))] = *(const bf16x8*)(valwT + (size_t)n * 128 + c * 8);
        }
        __syncthreads();

        int row = m0 + wv * 16 + r;
        int mg = min(row, MVAL - 1);
        const float* pA = ms + (size_t)mg * 128;
        float bia[8];
#pragma unroll
        for (int j = 0; j < 8; ++j) bia[j] = valb[j * 16 + r];

        f32x4 acc[8];
#pragma unroll
        for (int j = 0; j < 8; ++j)
#pragma unroll
            for (int e = 0; e < 4; ++e) acc[j][e] = 0.f;

#pragma unroll
        for (int ks = 0; ks < 4; ++ks) {
            const float* p = pA + ks * 32 + q * 8;
            float4 aa = *(const float4*)p;
            float4 bb = *(const float4*)(p + 4);
            bf16x8 af;
            af[0] = (short)f2bf(aa.x); af[1] = (short)f2bf(aa.y);
            af[2] = (short)f2bf(aa.z); af[3] = (short)f2bf(aa.w);
            af[4] = (short)f2bf(bb.x); af[5] = (short)f2bf(bb.y);
            af[6] = (short)f2bf(bb.z); af[7] = (short)f2bf(bb.w);
            bf16x8 bfr[8];
#pragma unroll
            for (int j = 0; j < 8; ++j)
                bfr[j] = Bs[(j * 16 + r) * 16 + ((ks * 4 + q) ^ r)];
#pragma unroll
            for (int j = 0; j < 8; ++j)
                acc[j] = __builtin_amdgcn_mfma_f32_16x16x32_bf16(af, bfr[j], acc[j], 0, 0, 0);
        }

        // direct head-major store: out row m = m0 + wv*16 + q*4 + e, col = j*16 + r (h=j)
#pragma unroll
        for (int e = 0; e < 4; ++e) {
            int m = m0 + wv * 16 + q * 4 + e;
            if (m < MVAL) {
                int cam = m / S_TOT;
                int s = m - cam * S_TOT;
                int pos, HW, sb;
                if (s < 11264)      { pos = s;          HW = 11264; sb = 0; }
                else if (s < 14080) { pos = s - 11264;  HW = 2816;  sb = 11264; }
                else if (s < 14784) { pos = s - 14080;  HW = 704;   sb = 14080; }
                else                { pos = s - 14784;  HW = 176;   sb = 14784; }
                size_t base = ((size_t)cam * S_TOT + sb) * CC + (size_t)pos * HDD + r;
#pragma unroll
                for (int j = 0; j < 8; ++j)
                    value[base + (size_t)j * (HW * HDD)] = f2bf(acc[j][e] + bia[j]);
            }
        }
        return;
    }

    // ---------------- conv role: one tap per block, A direct from global ----------------
    int tap = bx >> 3;          // 0..26
    int q0 = (bx & 7) * 128;    // query block
    int dz = tap / 9 - 1, dy = (tap / 3) % 3 - 1, dx = tap % 3 - 1;

    if (tid < 128) {
        int f = flatidx[q0 + tid];
        int nx = (f >> 10) + dz, ny = ((f >> 5) & 31) + dy, nz = (f & 31) + dx;
        bool ok = (nx >= 0 && nx < GG && ny >= 0 && ny < GG && nz >= 0 && nz < GG);
        int nf = ok ? (nx * GG + ny) * GG + nz : 0;
        nbase[tid] = nf;
        nscale[tid] = ok ? 1.0f / fmaxf(cnt[nf], 1.0f) : 0.f;
    }
    const unsigned short* Wt = WT + (size_t)tap * CC * CC;
#pragma unroll
    for (int it = 0; it < 8; ++it) {
        int idx = tid + it * 256;
        int n = idx >> 4, c = idx & 15;
        Bs[n * 16 + (c ^ (n & 15))] = *(const bf16x8*)(Wt + (size_t)n * CC + c * 8);
    }
    __syncthreads();

    int wr = (wv >> 1) * 64, wc = (wv & 1) * 64;
    f32x4 acc[4][4];
#pragma unroll
    for (int i = 0; i < 4; ++i)
#pragma unroll
        for (int j = 0; j < 4; ++j)
#pragma unroll
            for (int e = 0; e < 4; ++e) acc[i][j][e] = 0.f;
#pragma unroll
    for (int ks = 0; ks < 4; ++ks) {
        bf16x8 bfr[4];
#pragma unroll
        for (int j = 0; j < 4; ++j)
            bfr[j] = Bs[(wc + j * 16 + r) * 16 + ((ks * 4 + q) ^ r)];
#pragma unroll
        for (int i = 0; i < 4; ++i) {
            int row = wr + i * 16 + r;
            const float* p = grid + (size_t)nbase[row] * CC + (ks * 4 + q) * 8;
            float s = nscale[row];
            float4 aa = *(const float4*)p;
            float4 bb = *(const float4*)(p + 4);
            bf16x8 af;
            af[0] = (short)f2bf(aa.x * s); af[1] = (short)f2bf(aa.y * s);
            af[2] = (short)f2bf(aa.z * s); af[3] = (short)f2bf(aa.w * s);
            af[4] = (short)f2bf(bb.x * s); af[5] = (short)f2bf(bb.y * s);
            af[6] = (short)f2bf(bb.z * s); af[7] = (short)f2bf(bb.w * s);
#pragma unroll
            for (int j = 0; j < 4; ++j)
                acc[i][j] = __builtin_amdgcn_mfma_f32_16x16x32_bf16(af, bfr[j], acc[i][j], 0, 0, 0);
        }
    }
    float* dst = convacc27 + (size_t)tap * NQ * CC;
#pragma unroll
    for (int i = 0; i < 4; ++i)
#pragma unroll
        for (int e = 0; e < 4; ++e) {
            int m = q0 + wr + i * 16 + q * 4 + e;
#pragma unroll
            for (int j = 0; j < 4; ++j) {
                int col = wc + j * 16 + r;
                dst[(size_t)m * CC + col] = acc[i][j][e];
            }
        }
}

// ---------------- D3: LN(conv) + refoff dots (parallel) + projection ----------------
__global__ void k_ln_conv_proj(const float* __restrict__ a, const float* __restrict__ convacc27,
                               const float* __restrict__ bconv,
                               const float* __restrict__ g, const float* __restrict__ be,
                               float* __restrict__ out, unsigned short* __restrict__ outbf,
                               const float* __restrict__ refw, const float* __restrict__ refb,
                               const float* __restrict__ gp, const float* __restrict__ l2i,
                               const float* __restrict__ depth,
                               const int* __restrict__ ih, const int* __restrict__ iw,
                               float* __restrict__ wm, float* __restrict__ r2u,
                               float* __restrict__ r2v) {
    __shared__ float w4[4];
    __shared__ float qrow[CC];
    __shared__ float ro[12];
    int n = blockIdx.x, c = threadIdx.x;
    float apart = 0.f;
#pragma unroll
    for (int t = 0; t < NTAP; ++t) apart += convacc27[((size_t)t * NQ + n) * CC + c];
    float x = a[n * CC + c] + gelu_tanh(apart + bconv[c]);
    float s = x;
#pragma unroll
    for (int d = 1; d < 64; d <<= 1) s += __shfl_xor(s, d);
    if ((c & 63) == 0) w4[c >> 6] = s;
    __syncthreads();
    float m = (w4[0] + w4[1]) * (1.0f / CC);
    float dd = x - m;
    float v = dd * dd;
#pragma unroll
    for (int d = 1; d < 64; d <<= 1) v += __shfl_xor(v, d);
    if ((c & 63) == 0) w4[2 + (c >> 6)] = v;
    __syncthreads();
    float var = (w4[2] + w4[3]) * (1.0f / CC);
    float qv = dd * rsqrtf(var + 1e-5f) * g[c] + be[c];
    out[n * CC + c] = qv;
    outbf[n * CC + c] = f2bf(qv);
    qrow[c] = qv;
    __syncthreads();
    // refoff dots: 12 dots x 8 threads x 16 elems + shfl reduce (width 8)
    if (c < 96) {
        int dg = c >> 3, ll = c & 7;
        float sacc = 0.f;
#pragma unroll
        for (int k = 0; k < 16; ++k) {
            int kk = ll * 16 + k;
            sacc += qrow[kk] * refw[kk * 12 + dg];
        }
#pragma unroll
        for (int d = 4; d; d >>= 1) sacc += __shfl_xor(sacc, d, 8);
        if (ll == 0) ro[dg] = sacc + refb[dg];
    }
    __syncthreads();
    if (c < 24) {
        int cam = c >> 2, r = c & 3;
        float fH = (float)(*ih), fW = (float)(*iw);
        const float* M = l2i + cam * 16;
        float px = gp[n * PROPN + 0] + ro[r * 3 + 0];
        float py = gp[n * PROPN + 1] + ro[r * 3 + 1];
        float pz = gp[n * PROPN + 2] + ro[r * 3 + 2];
        float p0 = M[0] * px + M[1] * py + M[2]  * pz + M[3];
        float p1 = M[4] * px + M[5] * py + M[6]  * pz + M[7];
        float p2 = M[8] * px + M[9] * py + M[10] * pz + M[11];
        float zc = fmaxf(p2, 1e-5f);
        float u = p0 / zc, vv = p1 / zc;
        bool valid = (p2 > 1e-5f) && (u >= 0.f) && (u < fW) && (vv >= 0.f) && (vv < fH);
        int iu = min(max((int)(u / fW * 176.f), 0), 175);
        int iv = min(max((int)(vv / fH * 64.f), 0), 63);
        float ds = depth[cam * 64 * 176 + iv * 176 + iu];
        int o = cam * (NQ * RR) + n * RR + r;
        wm[o]  = valid ? expf(-fabsf(p2 - ds)) : 0.f;
        r2u[o] = u / fW;
        r2v[o] = vv / fH;
    }
}

// ---------------- D4: off + attn GEMMs, 64-row m-blocks (384 blocks) ----------
__global__ __launch_bounds__(256) void k_qhead(
    const unsigned short* __restrict__ Abf,
    const unsigned short* __restrict__ offwT, const float* __restrict__ offb,
    unsigned short* __restrict__ offsb,
    const unsigned short* __restrict__ awwT, const float* __restrict__ awb,
    unsigned short* __restrict__ attn)
{
    __shared__ bf16x8 Bs[128 * 16];   // 32 KB
    int bx = blockIdx.x, tid = threadIdx.x;
    int lane = tid & 63, wv = tid >> 6;
    int r = lane & 15, q = lane >> 4;
    bool isoff = bx < 16;
    int n0 = (isoff ? bx : (bx - 16)) * 128;
    const unsigned short* WT = isoff ? offwT : awwT;
    int m0 = blockIdx.y * 64;
    int mw = m0 + wv * 16;

#pragma unroll
    for (int it = 0; it < 8; ++it) {
        int idx = tid + it * 256;
        int n = idx >> 4, c = idx & 15;
        Bs[n * 16 + (c ^ (n & 15))] = *(const bf16x8*)(WT + (size_t)(n0 + n) * 128 + c * 8);
    }
    __syncthreads();

    f32x4 acc[8];
#pragma unroll
    for (int j = 0; j < 8; ++j)
#pragma unroll
        for (int e = 0; e < 4; ++e) acc[j][e] = 0.f;

#pragma unroll
    for (int ks = 0; ks < 4; ++ks) {
        bf16x8 af = *(const bf16x8*)(Abf + (size_t)(mw + r) * 128 + (ks * 4 + q) * 8);
#pragma unroll
        for (int j = 0; j < 8; ++j) {
            bf16x8 b = Bs[(j * 16 + r) * 16 + ((ks * 4 + q) ^ r)];
            acc[j] = __builtin_amdgcn_mfma_f32_16x16x32_bf16(af, b, acc[j], 0, 0, 0);
        }
    }

    float bia[8];
    const float* bsrc = isoff ? offb : awb;
#pragma unroll
    for (int j = 0; j < 8; ++j) bia[j] = bsrc[n0 + j * 16 + r];

    if (isoff) {
#pragma unroll
        for (int e = 0; e < 4; ++e) {
            int m = mw + q * 4 + e;
            unsigned short* orow = offsb + (size_t)m * 2048 + n0;
#pragma unroll
            for (int j = 0; j < 8; ++j)
                orow[j * 16 + r] = f2bf(acc[j][e] + bia[j]);
        }
    } else {
#pragma unroll
        for (int e = 0; e < 4; ++e) {
            float mx = -1e30f;
#pragma unroll
            for (int j = 0; j < 8; ++j) mx = fmaxf(mx, acc[j][e] + bia[j]);
#pragma unroll
            for (int d = 1; d < 16; d <<= 1) mx = fmaxf(mx, __shfl_xor(mx, d));
            float ex[8];
            float sum = 0.f;
#pragma unroll
            for (int j = 0; j < 8; ++j) { ex[j] = expf(acc[j][e] + bia[j] - mx); sum += ex[j]; }
#pragma unroll
            for (int d = 1; d < 16; d <<= 1) sum += __shfl_xor(sum, d);
            float inv = 1.0f / sum;
            int m = mw + q * 4 + e;
            unsigned short* orow = attn + (size_t)m * 1024 + n0;
#pragma unroll
            for (int j = 0; j < 8; ++j)
                orow[j * 16 + r] = f2bf(ex[j] * inv);
        }
    }
}

// ---------------- deformable sampling, head-major value, 512 threads (cr split) ----------
__global__ __launch_bounds__(512) void k_sample(
                         const unsigned short* __restrict__ value,
                         const unsigned short* __restrict__ offsb,
                         const unsigned short* __restrict__ attn,
                         const float* __restrict__ wm,
                         const float* __restrict__ r2u, const float* __restrict__ r2v,
                         float* __restrict__ sampout) {
    const int Wl_[4] = {176, 88, 44, 22};
    const int Hl_[4] = {64, 32, 16, 8};
    const int s0_[4] = {0, 11264, 14080, 14784};
    int n = blockIdx.x, tid = threadIdx.x;
    __shared__ float s_attn[1024];
    __shared__ float s_offs[2048];
    __shared__ float s_wm[24], s_ru[24], s_rv[24];
    __shared__ float part[HHD][HDD];

    if (tid < 128) {
        bf16x8 v = *(const bf16x8*)(attn + (size_t)n * 1024 + tid * 8);
#pragma unroll
        for (int d = 0; d < 8; ++d) s_attn[tid * 8 + d] = bf2f(v[d]);
    }
    if (tid < 256) {
        bf16x8 v = *(const bf16x8*)(offsb + (size_t)n * 2048 + tid * 8);
#pragma unroll
        for (int d = 0; d < 8; ++d) s_offs[tid * 8 + d] = bf2f(v[d]);
    }
    if (tid < 24) {
        int cam = tid >> 2, r = tid & 3;
        int o = cam * (NQ * RR) + n * RR + r;
        s_wm[tid] = wm[o]; s_ru[tid] = r2u[o]; s_rv[tid] = r2v[o];
    }
    __syncthreads();

    int half = tid >> 8;          // 0: cr 0-11, 1: cr 12-23
    int t8 = tid & 255;
    int h = t8 >> 5, slot = t8 & 31;
    int l = slot >> 3, p = slot & 7;
    int Wl = Wl_[l], Hl = Hl_[l];
    float fWl = (float)Wl, fHl = (float)Hl;
    size_t planeC = (size_t)s0_[l] * CC + (size_t)h * (Hl * Wl * HDD);
    float acc[16];
#pragma unroll
    for (int d = 0; d < 16; ++d) acc[d] = 0.f;

    for (int cr = half * 12; cr < half * 12 + 12; ++cr) {
        int cam = cr >> 2, r = cr & 3;
        float ws = s_attn[h * 128 + r * 32 + l * 8 + p] * s_wm[cr];
        if (ws == 0.f) continue;
        float ox = s_offs[h * 256 + r * 64 + l * 16 + p * 2 + 0];
        float oy = s_offs[h * 256 + r * 64 + l * 16 + p * 2 + 1];
        float x = s_ru[cr] * fWl + ox - 0.5f;
        float y = s_rv[cr] * fHl + oy - 0.5f;
        float xf = floorf(x), yf = floorf(y);
        float wx = x - xf, wy = y - yf;
        int x0 = min(max((int)xf, 0), Wl - 1);
        int x1 = min(max((int)xf + 1, 0), Wl - 1);
        int y0 = min(max((int)yf, 0), Hl - 1);
        int y1 = min(max((int)yf + 1, 0), Hl - 1);
        const unsigned short* base = value + (size_t)cam * S_TOT * CC + planeC;
        const unsigned short* p00 = base + (size_t)(y0 * Wl + x0) * HDD;
        const unsigned short* p01 = base + (size_t)(y0 * Wl + x1) * HDD;
        const unsigned short* p10 = base + (size_t)(y1 * Wl + x0) * HDD;
        const unsigned short* p11 = base + (size_t)(y1 * Wl + x1) * HDD;
        float w00 = ws * (1.f - wx) * (1.f - wy);
        float w01 = ws * wx * (1.f - wy);
        float w10 = ws * (1.f - wx) * wy;
        float w11 = ws * wx * wy;
        bf16x8 va0 = *(const bf16x8*)p00, va1 = *(const bf16x8*)(p00 + 8);
        bf16x8 vb0 = *(const bf16x8*)p01, vb1 = *(const bf16x8*)(p01 + 8);
        bf16x8 vc0 = *(const bf16x8*)p10, vc1 = *(const bf16x8*)(p10 + 8);
        bf16x8 vd0 = *(const bf16x8*)p11, vd1 = *(const bf16x8*)(p11 + 8);
#pragma unroll
        for (int d = 0; d < 8; ++d)
            acc[d] += w00 * bf2f(va0[d]) + w01 * bf2f(vb0[d]) + w10 * bf2f(vc0[d]) + w11 * bf2f(vd0[d]);
#pragma unroll
        for (int d = 0; d < 8; ++d)
            acc[8 + d] += w00 * bf2f(va1[d]) + w01 * bf2f(vb1[d]) + w10 * bf2f(vc1[d]) + w11 * bf2f(vd1[d]);
    }

#pragma unroll
    for (int d = 0; d < 16; ++d) {
        float a = acc[d];
#pragma unroll
        for (int s = 16; s >= 1; s >>= 1) a += __shfl_xor(a, s, 32);
        acc[d] = a;
    }
    if (half == 1 && slot == 0) {
#pragma unroll
        for (int d = 0; d < 16; ++d) part[h][d] = acc[d];
    }
    __syncthreads();
    if (half == 0 && slot == 0) {
#pragma unroll
        for (int d = 0; d < 16; ++d)
            sampout[(size_t)n * CC + h * HDD + d] = acc[d] + part[h][d];
    }
}

// ---------------- fused tail: M=16/block, 64 blocks x 512 threads (8 waves, 16 cols/wave) --
__global__ __launch_bounds__(512) void k_tail(
    const float* __restrict__ sampout,
    const unsigned short* __restrict__ outwT, const float* __restrict__ outb,
    const float* __restrict__ q1, const float* __restrict__ ang, const float* __restrict__ anb,
    const unsigned short* __restrict__ f1wT, const float* __restrict__ f1b,
    const unsigned short* __restrict__ f2wT, const float* __restrict__ f2b,
    const float* __restrict__ fng, const float* __restrict__ fnb,
    const unsigned short* __restrict__ p1wT, const float* __restrict__ p1b,
    const unsigned short* __restrict__ p2wT, const float* __restrict__ p2bp,
    const float* __restrict__ gp, float* __restrict__ outq, float* __restrict__ outp)
{
    __shared__ bf16x8 As[16 * 16];       // 4 KB
    __shared__ bf16x8 Aff[16 * 64];      // 16 KB  (FFN1 out 16x512; aliased as As2 16x128)
    __shared__ float xrow[16 * 128];     // 8 KB
    __shared__ float q2s[16 * 128];      // 8 KB   -> total 36 KB
    unsigned short* Affu = (unsigned short*)Aff;
    unsigned short* As2u = (unsigned short*)Aff;
    int tid = threadIdx.x, m0 = blockIdx.x * 16;
    int lane = tid & 63, wv = tid >> 6;  // 8 waves
    int wc = wv * 16;                    // each wave owns 16 output cols
    int r = lane & 15, q = lane >> 4;
    int lrow = tid >> 5, ls = tid & 31;  // LN: 32 threads per row

    // pre-issue GEMM1 B (out-proj) into registers before any barrier
    bf16x8 b1[4];
#pragma unroll
    for (int ks = 0; ks < 4; ++ks)
        b1[ks] = *(const bf16x8*)(outwT + (size_t)(wc + r) * 128 + (ks * 4 + q) * 8);

    // stage A (sampout rows m0..m0+15), 256 threads = 16 rows x 16 chunks
    if (tid < 256) {
        int m = tid >> 4, c = tid & 15;
        const float* p = sampout + (size_t)(m0 + m) * 128 + c * 8;
        float4 a = *(const float4*)p;
        float4 b = *(const float4*)(p + 4);
        bf16x8 u;
        u[0] = (short)f2bf(a.x); u[1] = (short)f2bf(a.y);
        u[2] = (short)f2bf(a.z); u[3] = (short)f2bf(a.w);
        u[4] = (short)f2bf(b.x); u[5] = (short)f2bf(b.y);
        u[6] = (short)f2bf(b.z); u[7] = (short)f2bf(b.w);
        As[m * 16 + (c ^ m)] = u;
    }
    __syncthreads();

    f32x4 acc;
    bf16x8 a4[4];
    // ---- GEMM1: out-proj ----
#pragma unroll
    for (int ks = 0; ks < 4; ++ks) a4[ks] = As[r * 16 + ((ks * 4 + q) ^ r)];
#pragma unroll
    for (int e = 0; e < 4; ++e) acc[e] = 0.f;
#pragma unroll
    for (int ks = 0; ks < 4; ++ks)
        acc = __builtin_amdgcn_mfma_f32_16x16x32_bf16(a4[ks], b1[ks], acc, 0, 0, 0);
#pragma unroll
    for (int e = 0; e < 4; ++e) {
        int ml = q * 4 + e;
        int cl = wc + r;
        xrow[ml * 128 + cl] = acc[e] + outb[cl] + q1[(size_t)(m0 + ml) * 128 + cl];
    }
    __syncthreads();

    // ---- LN1 -> q2s ----
    {
        float* xr = xrow + lrow * 128;
        float sum = 0.f;
#pragma unroll
        for (int e = ls; e < 128; e += 32) sum += xr[e];
#pragma unroll
        for (int d = 16; d; d >>= 1) sum += __shfl_xor(sum, d, 32);
        float mean = sum * (1.0f / 128.0f);
        float var = 0.f;
#pragma unroll
        for (int e = ls; e < 128; e += 32) { float dd = xr[e] - mean; var += dd * dd; }
#pragma unroll
        for (int d = 16; d; d >>= 1) var += __shfl_xor(var, d, 32);
        float rstd = rsqrtf(var * (1.0f / 128.0f) + 1e-5f);
#pragma unroll
        for (int e = ls; e < 128; e += 32)
            q2s[lrow * 128 + e] = (xr[e] - mean) * rstd * ang[e] + anb[e];
    }
    __syncthreads();
    if (tid < 256) {   // pack q2 -> As
        int m = tid >> 4, c = tid & 15;
        const float* p = q2s + m * 128 + c * 8;
        bf16x8 u;
#pragma unroll
        for (int d = 0; d < 8; ++d) u[d] = (short)f2bf(p[d]);
        As[m * 16 + (c ^ m)] = u;
    }
    __syncthreads();

    // ---- GEMM2: FFN1 over 4 col-chunks, reg-double-buffered B, no barriers ----
#pragma unroll
    for (int ks = 0; ks < 4; ++ks) a4[ks] = As[r * 16 + ((ks * 4 + q) ^ r)];
    bf16x8 bcur[4];
#pragma unroll
    for (int ks = 0; ks < 4; ++ks)
        bcur[ks] = *(const bf16x8*)(f1wT + (size_t)(wc + r) * 128 + (ks * 4 + q) * 8);
#pragma unroll
    for (int nt = 0; nt < 4; ++nt) {
        bf16x8 bnx[4];
        if (nt < 3) {
#pragma unroll
            for (int ks = 0; ks < 4; ++ks)
                bnx[ks] = *(const bf16x8*)(f1wT + (size_t)(nt + 1) * 16384
                                            + (size_t)(wc + r) * 128 + (ks * 4 + q) * 8);
        }
#pragma unroll
        for (int e = 0; e < 4; ++e) acc[e] = 0.f;
#pragma unroll
        for (int ks = 0; ks < 4; ++ks)
            acc = __builtin_amdgcn_mfma_f32_16x16x32_bf16(a4[ks], bcur[ks], acc, 0, 0, 0);
#pragma unroll
        for (int e = 0; e < 4; ++e) {
            int ml = q * 4 + e;
            int col = nt * 128 + wc + r;
            float v = gelu_tanh(acc[e] + f1b[col]);
            Affu[(ml * 64 + ((col >> 3) ^ ml)) * 8 + (col & 7)] = f2bf(v);
        }
        if (nt < 3) {
#pragma unroll
            for (int ks = 0; ks < 4; ++ks) bcur[ks] = bnx[ks];
        }
    }
    __syncthreads();

    // ---- GEMM3: FFN2 (K=512) accumulate over 4 k-chunks, reg-double-buffered B ----
#pragma unroll
    for (int e = 0; e < 4; ++e) acc[e] = 0.f;
#pragma unroll
    for (int ks = 0; ks < 4; ++ks)
        bcur[ks] = *(const bf16x8*)(f2wT + (size_t)(wc + r) * 512 + (ks * 4 + q) * 8);
#pragma unroll
    for (int kc = 0; kc < 4; ++kc) {
        bf16x8 bnx[4];
        if (kc < 3) {
#pragma unroll
            for (int ks = 0; ks < 4; ++ks)
                bnx[ks] = *(const bf16x8*)(f2wT + (size_t)(wc + r) * 512
                                            + ((kc + 1) * 16 + ks * 4 + q) * 8);
        }
#pragma unroll
        for (int ks = 0; ks < 4; ++ks) {
            bf16x8 af = Aff[r * 64 + ((kc * 16 + ks * 4 + q) ^ r)];
            acc = __builtin_amdgcn_mfma_f32_16x16x32_bf16(af, bcur[ks], acc, 0, 0, 0);
        }
        if (kc < 3) {
#pragma unroll
            for (int ks = 0; ks < 4; ++ks) bcur[ks] = bnx[ks];
        }
    }
#pragma unroll
    for (int e = 0; e < 4; ++e) {
        int ml = q * 4 + e;
        int cl = wc + r;
        xrow[ml * 128 + cl] = acc[e] + f2b[cl] + q2s[ml * 128 + cl];
    }
    __syncthreads();

    // ---- LN2 -> outq + q2s ----
    {
        float* xr = xrow + lrow * 128;
        float sum = 0.f;
#pragma unroll
        for (int e = ls; e < 128; e += 32) sum += xr[e];
#pragma unroll
        for (int d = 16; d; d >>= 1) sum += __shfl_xor(sum, d, 32);
        float mean = sum * (1.0f / 128.0f);
        float var = 0.f;
#pragma unroll
        for (int e = ls; e < 128; e += 32) { float dd = xr[e] - mean; var += dd * dd; }
#pragma unroll
        for (int d = 16; d; d >>= 1) var += __shfl_xor(var, d, 32);
        float rstd = rsqrtf(var * (1.0f / 128.0f) + 1e-5f);
        float* oq = outq + (size_t)(m0 + lrow) * 128;
#pragma unroll
        for (int e = ls; e < 128; e += 32) {
            float v = (xr[e] - mean) * rstd * fng[e] + fnb[e];
            oq[e] = v;
            q2s[lrow * 128 + e] = v;
        }
    }
    __syncthreads();
    if (tid < 256) {   // pack LN2 -> As
        int m = tid >> 4, c = tid & 15;
        const float* p = q2s + m * 128 + c * 8;
        bf16x8 u;
#pragma unroll
        for (int d = 0; d < 8; ++d) u[d] = (short)f2bf(p[d]);
        As[m * 16 + (c ^ m)] = u;
    }
    __syncthreads();

    // ---- GEMM4: p1 -> gelu -> As2 (aliases Aff) ----
#pragma unroll
    for (int ks = 0; ks < 4; ++ks) a4[ks] = As[r * 16 + ((ks * 4 + q) ^ r)];
    bf16x8 bcur2[4];
#pragma unroll
    for (int ks = 0; ks < 4; ++ks)
        bcur2[ks] = *(const bf16x8*)(p1wT + (size_t)(wc + r) * 128 + (ks * 4 + q) * 8);
    // pre-issue p2 B loads (held in b1) to hide latency under GEMM4
#pragma unroll
    for (int ks = 0; ks < 4; ++ks)
        b1[ks] = *(const bf16x8*)(p2wT + (size_t)(wc + r) * 128 + (ks * 4 + q) * 8);
#pragma unroll
    for (int e = 0; e < 4; ++e) acc[e] = 0.f;
#pragma unroll
    for (int ks = 0; ks < 4; ++ks)
        acc = __builtin_amdgcn_mfma_f32_16x16x32_bf16(a4[ks], bcur2[ks], acc, 0, 0, 0);
#pragma unroll
    for (int e = 0; e < 4; ++e) {
        int ml = q * 4 + e;
        int cl = wc + r;
        float v = gelu_tanh(acc[e] + p1b[cl]);
        As2u[(ml * 16 + ((cl >> 3) ^ ml)) * 8 + (cl & 7)] = f2bf(v);
    }
    __syncthreads();

    // ---- GEMM5: p2 + gp resid -> outp ----
#pragma unroll
    for (int e = 0; e < 4; ++e) acc[e] = 0.f;
#pragma unroll
    for (int ks = 0; ks < 4; ++ks) {
        bf16x8 af = Aff[r * 16 + ((ks * 4 + q) ^ r)];   // As2 view
        acc = __builtin_amdgcn_mfma_f32_16x16x32_bf16(af, b1[ks], acc, 0, 0, 0);
    }
#pragma unroll
    for (int e = 0; e < 4; ++e) {
        int m = m0 + q * 4 + e;
        int cl = wc + r;
        if (cl < PROPN)
            outp[(size_t)m * PROPN + cl] = acc[e] + p2bp[cl] + gp[(size_t)m * PROPN + cl];
    }
}

// ---------------- launch ----------------
extern "C" void kernel_launch(void* const* d_in, const int* in_sizes, int n_in,
                              void* d_out, int out_size, void* d_ws, size_t ws_size,
                              hipStream_t stream) {
    const float* query = (const float*)d_in[0];
    const float* gp    = (const float*)d_in[1];
    const float* ms    = (const float*)d_in[2];
    const float* depth = (const float*)d_in[3];
    const float* l2i   = (const float*)d_in[4];
    const int*   ih    = (const int*)d_in[5];
    const int*   iw    = (const int*)d_in[6];
    const float* Wsc   = (const float*)d_in[7];
    const float* bsc   = (const float*)d_in[8];
    const float* scg   = (const float*)d_in[9];
    const float* scb   = (const float*)d_in[10];
    const float* refw  = (const float*)d_in[11];
    const float* refb  = (const float*)d_in[12];
    const float* offw  = (const float*)d_in[13];
    const float* offbi = (const float*)d_in[14];
    const float* aww   = (const float*)d_in[15];
    const float* awb   = (const float*)d_in[16];
    const float* valw  = (const float*)d_in[17];
    const float* valb  = (const float*)d_in[18];
    const float* outw  = (const float*)d_in[19];
    const float* outb  = (const float*)d_in[20];
    const float* ang   = (const float*)d_in[21];
    const float* anb   = (const float*)d_in[22];
    const float* f1w   = (const float*)d_in[23];
    const float* f1b   = (const float*)d_in[24];
    const float* f2w   = (const float*)d_in[25];
    const float* f2b   = (const float*)d_in[26];
    const float* fng   = (const float*)d_in[27];
    const float* fnb   = (const float*)d_in[28];
    const float* p1w   = (const float*)d_in[29];
    const float* p1b   = (const float*)d_in[30];
    const float* p2w   = (const float*)d_in[31];
    const float* p2b   = (const float*)d_in[32];

    float* outq = (float*)d_out;            // 1024*128
    float* outp = outq + NQ * CC;           // 1024*28

    float* ws = (float*)d_ws;
    size_t o = 0;
    float* grid    = ws + o; o += (size_t)GG * GG * GG * CC;
    float* cnt     = ws + o; o += GG * GG * GG;
    size_t zero_floats = o;                 // zero grid+cnt only
    int*   flatidx = (int*)(ws + o); o += NQ;
    float* convacc27 = ws + o; o += (size_t)NTAP * NQ * CC;
    float* q1      = ws + o; o += NQ * CC;
    float* wm      = ws + o; o += CAM * NQ * RR;
    float* r2u     = ws + o; o += CAM * NQ * RR;
    float* r2v     = ws + o; o += CAM * NQ * RR;
    float* sampout = ws + o; o += NQ * CC;
    float* p2bp    = ws + o; o += 128;
    unsigned short* u16base = (unsigned short*)(ws + o);
    size_t uo = 0;
    unsigned short* value = u16base + uo; uo += (size_t)CAM * S_TOT * CC;
    unsigned short* offsb = u16base + uo; uo += (size_t)NQ * 2048;
    unsigned short* attn  = u16base + uo; uo += (size_t)NQ * 1024;
    unsigned short* q1bf  = u16base + uo; uo += (size_t)NQ * CC;
    unsigned short* offwT = u16base + uo; uo += (size_t)2048 * 128;
    unsigned short* awwT  = u16base + uo; uo += (size_t)1024 * 128;
    unsigned short* valwT = u16base + uo; uo += 128 * 128;
    unsigned short* outwT = u16base + uo; uo += 128 * 128;
    unsigned short* f1wT  = u16base + uo; uo += 512 * 128;
    unsigned short* f2wT  = u16base + uo; uo += 128 * 512;
    unsigned short* p1wT  = u16base + uo; uo += 128 * 128;
    unsigned short* p2wT  = u16base + uo; uo += 128 * 128;
    unsigned short* WscT  = u16base + uo; uo += (size_t)27 * 128 * 128;
    (void)ws_size; (void)in_sizes; (void)n_in; (void)out_size;

    hipMemsetAsync(ws, 0, zero_floats * sizeof(float), stream);

    // D1: z<63 all weight transposes; z in [63,191): voxel scatter (2 queries/block)
    k_wt_scatter<<<dim3(2, 2, 63 + 128), 256, 0, stream>>>(
        Wsc, WscT, valw, valwT, outw, outwT, p1w, p1wT, f1w, f1wT, f2w, f2wT,
        offw, offwT, aww, awwT, p2w, p2wT, p2b, p2bp,
        query, gp, grid, cnt, flatidx);

    // D2: bx<216 conv per-tap (A direct); bx>=216 valproj (33 KB LDS -> 4 blocks/CU)
    k_conv_val<<<dim3(NCVB + NVB), 256, 0, stream>>>(
        grid, cnt, flatidx, WscT, convacc27,
        ms, valwT, valb, value);

    // D3: LN + refoff + projection
    k_ln_conv_proj<<<NQ, CC, 0, stream>>>(
        query, convacc27, bsc, scg, scb, q1, q1bf,
        refw, refb, gp, l2i, depth, ih, iw, wm, r2u, r2v);

    // D4: off/attn GEMMs, 64-row m-blocks
    k_qhead<<<dim3(24, 16), 256, 0, stream>>>(q1bf, offwT, offbi, offsb, awwT, awb, attn);

    k_sample<<<NQ, 512, 0, stream>>>(value, offsb, attn, wm, r2u, r2v, sampout);

    k_tail<<<64, 512, 0, stream>>>(sampout, outwT, outb, q1, ang, anb,
                                   f1wT, f1b, f2wT, f2b, fng, fnb,
                                   p1wT, p1b, p2wT, p2bp, gp, outq, outp);
}